// Round 8
// baseline (106.685 us; speedup 1.0000x reference)
//
#include <hip/hip_runtime.h>
#include <math.h>

#define BB 4
#define TT 1024
#define DD 512
#define HH 8
#define DHH 64

typedef short bf8_t __attribute__((ext_vector_type(8)));
typedef float f32x4 __attribute__((ext_vector_type(4)));

__device__ __forceinline__ float softplus_f(float z) {
    return fmaxf(z, 0.f) + log1pf(__expf(-fabsf(z)));
}

__device__ __forceinline__ unsigned short f2bf(float f) {
    union { float f; unsigned int u; } v; v.f = f;
    return (unsigned short)((v.u + 0x7FFFu + ((v.u >> 16) & 1u)) >> 16);
}

// Raw barrier: LDS visibility only — does NOT drain vmcnt (global store acks /
// prefetch loads stay in flight across it). Correct where nothing re-reads
// in-kernel global stores; LDS deps are covered by lgkmcnt(0). Compiler still
// inserts vmcnt waits before ds_write of loaded regs (data dep).
__device__ __forceinline__ void bar_lgkm() {
    asm volatile("s_waitcnt lgkmcnt(0)" ::: "memory");
    __builtin_amdgcn_s_barrier();
}

// ---------------------------------------------------------------------------
// K0: fused prep. blocks [0,1024): cast x->bf16; [1024,2048): transpose one
// 32x32 tile of Wq/Wk/Wv/Wo; [2048]: Ws -> wt rows 1536..1543.
// ---------------------------------------------------------------------------
__global__ __launch_bounds__(256) void prep_kernel(
    const float* __restrict__ x,
    const float* __restrict__ Wq, const float* __restrict__ Wk,
    const float* __restrict__ Wv, const float* __restrict__ Wo,
    const float* __restrict__ Ws,
    unsigned short* __restrict__ xbf,
    unsigned short* __restrict__ wt, unsigned short* __restrict__ woT)
{
    __shared__ float tile[32][33];
    const int tid = threadIdx.x;
    int b = blockIdx.x;

    if (b < 1024) {                       // cast x
        int i = b * 256 + tid;
        float4 a = *(const float4*)&x[(size_t)i * 8];
        float4 c = *(const float4*)&x[(size_t)i * 8 + 4];
        union { unsigned short u[8]; int4 v; } o;
        o.u[0] = f2bf(a.x); o.u[1] = f2bf(a.y); o.u[2] = f2bf(a.z); o.u[3] = f2bf(a.w);
        o.u[4] = f2bf(c.x); o.u[5] = f2bf(c.y); o.u[6] = f2bf(c.z); o.u[7] = f2bf(c.w);
        *(int4*)&xbf[(size_t)i * 8] = o.v;
        return;
    }
    b -= 1024;
    if (b < 1024) {                       // transpose 32x32 tile
        int z = b >> 8, t = b & 255;
        const float* W = (z == 0) ? Wq : (z == 1) ? Wk : (z == 2) ? Wv : Wo;
        unsigned short* dst = (z < 3) ? (wt + (size_t)z * 512 * 512) : woT;
        int k0 = (t >> 4) * 32, n0 = (t & 15) * 32;
        int ty = tid >> 3, tx = tid & 7;
        float4 v = *(const float4*)&W[(size_t)(k0 + ty) * 512 + n0 + tx * 4];
        tile[ty][tx*4+0] = v.x; tile[ty][tx*4+1] = v.y;
        tile[ty][tx*4+2] = v.z; tile[ty][tx*4+3] = v.w;
        __syncthreads();
        ushort4 o;
        o.x = f2bf(tile[tx*4+0][ty]);
        o.y = f2bf(tile[tx*4+1][ty]);
        o.z = f2bf(tile[tx*4+2][ty]);
        o.w = f2bf(tile[tx*4+3][ty]);
        *(ushort4*)&dst[(size_t)(n0 + ty) * 512 + k0 + tx * 4] = o;
        return;
    }
    // Ws [512][8] -> wt rows 1536..1543
    #pragma unroll
    for (int i = 0; i < 16; ++i) {
        int idx = i * 256 + tid;          // = k*8 + n
        int k = idx >> 3, n = idx & 7;
        wt[(size_t)(1536 + n) * 512 + k] = f2bf(Ws[idx]);
    }
}

// ---------------------------------------------------------------------------
// K1: proj GEMM via MFMA: C[4096,1544] = xbf @ wt^T.
// Double-buffered LDS, reg-prefetch, one lgkm-only barrier per K-step.
// ---------------------------------------------------------------------------
__global__ __launch_bounds__(256) void proj_mfma_kernel(
    const unsigned short* __restrict__ xbf,   // [4096][512]
    const unsigned short* __restrict__ wt,    // [1600][512], rows 0..1543 valid
    const float* __restrict__ bq, const float* __restrict__ bk,
    const float* __restrict__ bv, const float* __restrict__ bs,
    unsigned short* __restrict__ qbf, unsigned short* __restrict__ kbf,
    unsigned short* __restrict__ vbf, float* __restrict__ sigma_out)
{
    __shared__ unsigned short a_s[2][64][64];
    __shared__ unsigned short b_s[2][64][64];
    const int tid = threadIdx.x;
    const int w = tid >> 6, l = tid & 63, lr = l & 15, lg = l >> 4;
    const int ct = blockIdx.x;          // 0..24
    const int m0 = blockIdx.y * 64;
    const int n0 = ct * 64;

    f32x4 acc[4];
    #pragma unroll
    for (int nb = 0; nb < 4; ++nb) acc[nb] = (f32x4){0.f, 0.f, 0.f, 0.f};

    int4 areg[2], breg[2];

    // prologue: stage k-chunk 0 into buffer 0
    #pragma unroll
    for (int rep = 0; rep < 2; ++rep) {
        int idx = rep * 256 + tid;
        int row = idx >> 3, cg = idx & 7;
        areg[rep] = *(const int4*)&xbf[(size_t)(m0 + row) * 512 + cg * 8];
        breg[rep] = *(const int4*)&wt[(size_t)(n0 + row) * 512 + cg * 8];
    }
    #pragma unroll
    for (int rep = 0; rep < 2; ++rep) {
        int idx = rep * 256 + tid;
        int row = idx >> 3, cg = idx & 7;
        *(int4*)&a_s[0][row][(cg ^ (row & 7)) * 8] = areg[rep];
        *(int4*)&b_s[0][row][(cg ^ (row & 7)) * 8] = breg[rep];
    }
    bar_lgkm();

    for (int kc = 0; kc < 8; ++kc) {
        const int cur = kc & 1;
        // 1. prefetch next k-chunk into regs
        if (kc < 7) {
            int k0 = (kc + 1) * 64;
            #pragma unroll
            for (int rep = 0; rep < 2; ++rep) {
                int idx = rep * 256 + tid;
                int row = idx >> 3, cg = idx & 7;
                areg[rep] = *(const int4*)&xbf[(size_t)(m0 + row) * 512 + k0 + cg * 8];
                breg[rep] = *(const int4*)&wt[(size_t)(n0 + row) * 512 + k0 + cg * 8];
            }
        }
        // 2. MFMA on current buffer
        #pragma unroll
        for (int ks = 0; ks < 2; ++ks) {
            int arow = w * 16 + lr;
            bf8_t af = *(const bf8_t*)&a_s[cur][arow][((ks*4 + lg) ^ (arow & 7)) * 8];
            #pragma unroll
            for (int nb = 0; nb < 4; ++nb) {
                int brow = nb * 16 + lr;
                bf8_t bf = *(const bf8_t*)&b_s[cur][brow][((ks*4 + lg) ^ (brow & 7)) * 8];
                acc[nb] = __builtin_amdgcn_mfma_f32_16x16x32_bf16(af, bf, acc[nb], 0, 0, 0);
            }
        }
        // 3. write prefetched chunk into other buffer; lgkm-only barrier
        if (kc < 7) {
            #pragma unroll
            for (int rep = 0; rep < 2; ++rep) {
                int idx = rep * 256 + tid;
                int row = idx >> 3, cg = idx & 7;
                *(int4*)&a_s[cur ^ 1][row][(cg ^ (row & 7)) * 8] = areg[rep];
                *(int4*)&b_s[cur ^ 1][row][(cg ^ (row & 7)) * 8] = breg[rep];
            }
            bar_lgkm();
        }
    }

    if (ct < 24) {
        const int seg = ct >> 3;
        const int h = ct & 7;
        const float* bias = (seg == 0) ? bq : (seg == 1) ? bk : bv;
        unsigned short* dst = (seg == 0) ? qbf : (seg == 1) ? kbf : vbf;
        const float sc = (seg == 0) ? 0.125f : 1.f;
        #pragma unroll
        for (int nb = 0; nb < 4; ++nb) {
            float bb = bias[h * 64 + nb * 16 + lr];
            #pragma unroll
            for (int r = 0; r < 4; ++r) {
                int m = m0 + w * 16 + lg * 4 + r;
                int b = m >> 10, t = m & 1023;
                dst[((size_t)((b*HH + h)*TT + t)) * 64 + nb * 16 + lr] =
                    f2bf((acc[nb][r] + bb) * sc);
            }
        }
    } else if (lr < 8) {
        float bb = bs[lr];
        #pragma unroll
        for (int r = 0; r < 4; ++r) {
            int m = m0 + w * 16 + lg * 4 + r;
            int b = m >> 10, t = m & 1023;
            sigma_out[(size_t)(b*HH + lr)*TT + t] = softplus_f(acc[0][r] + bb) + 1e-6f;
        }
    }
}

// ---------------------------------------------------------------------------
// K2: fused attention + prior (unchanged from round 7's 105 µs version).
// ---------------------------------------------------------------------------
__global__ __launch_bounds__(256) void attn_kernel(
    const unsigned short* __restrict__ qbf,
    const unsigned short* __restrict__ kbf,
    const unsigned short* __restrict__ vbf,
    const float* __restrict__ sigma,
    float* __restrict__ series, float* __restrict__ prior,
    unsigned short* __restrict__ obf)
{
    __shared__ unsigned short k_lds[2][64][72];   // K tile [s][dh], dbuf
    __shared__ unsigned short v_lds[2][64][64];   // V^T tile [dh][s] swizzled, dbuf
    __shared__ unsigned short p_lds[4][16][72];   // per-wave P tile [qrow][s]

    const int tid = threadIdx.x;
    const int w  = tid >> 6, l = tid & 63;
    const int lr = l & 15,  lg = l >> 4;
    const int bh = blockIdx.y;
    const int qr = blockIdx.x * 64 + w * 16;

    const int srow = tid >> 3, scg = tid & 7;     // staging coords
    const unsigned short* kb = kbf + (size_t)bh * TT * 64;
    const unsigned short* vb = vbf + (size_t)bh * TT * 64;

    bf8_t aq[2];
    {
        const unsigned short* qrow = &qbf[((size_t)bh * TT + qr + lr) * 64];
        aq[0] = *(const bf8_t*)&qrow[lg * 8];
        aq[1] = *(const bf8_t*)&qrow[32 + lg * 8];
    }

    int4 kreg0, kreg1, vreg0, vreg1;

    // ---------------- sweep 1: row sums ----------------
    float psum[4] = {0.f, 0.f, 0.f, 0.f};
    kreg0 = *(const int4*)&kb[(size_t)srow * 64 + scg * 8];
    kreg1 = *(const int4*)&kb[(size_t)(32 + srow) * 64 + scg * 8];
    *(int4*)&k_lds[0][srow][scg * 8] = kreg0;
    *(int4*)&k_lds[0][32 + srow][scg * 8] = kreg1;
    bar_lgkm();

    for (int st = 0; st < 16; ++st) {
        const int cur = st & 1;
        if (st < 15) {
            kreg0 = *(const int4*)&kb[(size_t)((st+1)*64 + srow) * 64 + scg * 8];
            kreg1 = *(const int4*)&kb[(size_t)((st+1)*64 + 32 + srow) * 64 + scg * 8];
        }
        #pragma unroll
        for (int nb = 0; nb < 4; ++nb) {
            f32x4 acc = {0.f, 0.f, 0.f, 0.f};
            #pragma unroll
            for (int c = 0; c < 2; ++c) {
                bf8_t bk = *(const bf8_t*)&k_lds[cur][nb * 16 + lr][c * 32 + lg * 8];
                acc = __builtin_amdgcn_mfma_f32_16x16x32_bf16(aq[c], bk, acc, 0, 0, 0);
            }
            #pragma unroll
            for (int r = 0; r < 4; ++r) psum[r] += __expf(acc[r]);
        }
        if (st < 15) {
            *(int4*)&k_lds[cur ^ 1][srow][scg * 8] = kreg0;
            *(int4*)&k_lds[cur ^ 1][32 + srow][scg * 8] = kreg1;
            bar_lgkm();
        }
    }
    #pragma unroll
    for (int r = 0; r < 4; ++r) {
        psum[r] += __shfl_xor(psum[r], 1);
        psum[r] += __shfl_xor(psum[r], 2);
        psum[r] += __shfl_xor(psum[r], 4);
        psum[r] += __shfl_xor(psum[r], 8);
    }
    float inv[4];
    #pragma unroll
    for (int r = 0; r < 4; ++r) inv[r] = 1.f / psum[r];

    // ---------------- sweep 2: series + PV + in-loop prior ----------------
    f32x4 oacc[4];
    #pragma unroll
    for (int nb = 0; nb < 4; ++nb) oacc[nb] = (f32x4){0.f, 0.f, 0.f, 0.f};

    kreg0 = *(const int4*)&kb[(size_t)srow * 64 + scg * 8];
    kreg1 = *(const int4*)&kb[(size_t)(32 + srow) * 64 + scg * 8];
    vreg0 = *(const int4*)&vb[(size_t)srow * 64 + scg * 8];
    vreg1 = *(const int4*)&vb[(size_t)(32 + srow) * 64 + scg * 8];
    *(int4*)&k_lds[0][srow][scg * 8] = kreg0;
    *(int4*)&k_lds[0][32 + srow][scg * 8] = kreg1;
    {
        const unsigned short* pv0 = (const unsigned short*)&vreg0;
        const unsigned short* pv1 = (const unsigned short*)&vreg1;
        #pragma unroll
        for (int j = 0; j < 8; ++j) {
            int row = scg * 8 + j;
            int g0 = ((srow >> 3) ^ j ^ scg) & 7;
            int g1 = ((srow >> 3) ^ 4 ^ j ^ scg) & 7;
            v_lds[0][row][g0 * 8 + (srow & 7)] = pv0[j];
            v_lds[0][row][g1 * 8 + (srow & 7)] = pv1[j];
        }
    }
    bar_lgkm();

    for (int st = 0; st < 16; ++st) {
        const int cur = st & 1;
        if (st < 15) {
            kreg0 = *(const int4*)&kb[(size_t)((st+1)*64 + srow) * 64 + scg * 8];
            kreg1 = *(const int4*)&kb[(size_t)((st+1)*64 + 32 + srow) * 64 + scg * 8];
            vreg0 = *(const int4*)&vb[(size_t)((st+1)*64 + srow) * 64 + scg * 8];
            vreg1 = *(const int4*)&vb[(size_t)((st+1)*64 + 32 + srow) * 64 + scg * 8];
        }

        #pragma unroll
        for (int nb = 0; nb < 4; ++nb) {
            f32x4 acc = {0.f, 0.f, 0.f, 0.f};
            #pragma unroll
            for (int c = 0; c < 2; ++c) {
                bf8_t bk = *(const bf8_t*)&k_lds[cur][nb * 16 + lr][c * 32 + lg * 8];
                acc = __builtin_amdgcn_mfma_f32_16x16x32_bf16(aq[c], bk, acc, 0, 0, 0);
            }
            #pragma unroll
            for (int r = 0; r < 4; ++r) {
                float e = __expf(acc[r]);
                series[((size_t)bh * TT + qr + lg * 4 + r) * TT + st * 64 + nb * 16 + lr]
                    = e * inv[r];
                p_lds[w][lg * 4 + r][nb * 16 + lr] = f2bf(e);
            }
        }

        bf8_t pa0 = *(const bf8_t*)&p_lds[w][lr][lg * 8];
        bf8_t pa1 = *(const bf8_t*)&p_lds[w][lr][32 + lg * 8];
        #pragma unroll
        for (int nb = 0; nb < 4; ++nb) {
            #pragma unroll
            for (int c = 0; c < 2; ++c) {
                int row = nb * 16 + lr;
                int gsw = ((c * 4 + lg) ^ (row & 7) ^ (row >> 3)) & 7;
                bf8_t bv = *(const bf8_t*)&v_lds[cur][row][gsw * 8];
                oacc[nb] = __builtin_amdgcn_mfma_f32_16x16x32_bf16(
                    (c == 0) ? pa0 : pa1, bv, oacc[nb], 0, 0, 0);
            }
        }

        {
            int t = qr + st;
            float sg = sigma[(size_t)bh * TT + t];
            float cc = 1.f / (2.f * (sg * sg + 1e-6f));
            float e[16]; float sum = 0.f;
            #pragma unroll
            for (int j = 0; j < 16; ++j) {
                float d = (float)(t - (j * 64 + l));
                e[j] = __expf(-(d * d) * cc);
                sum += e[j];
            }
            sum += __shfl_xor(sum, 32);
            sum += __shfl_xor(sum, 16);
            sum += __shfl_xor(sum, 8);
            sum += __shfl_xor(sum, 4);
            sum += __shfl_xor(sum, 2);
            sum += __shfl_xor(sum, 1);
            float pinv = 1.f / (sum + 1e-9f);
            float* pr = prior + ((size_t)bh * TT + t) * TT;
            #pragma unroll
            for (int j = 0; j < 16; ++j) pr[j * 64 + l] = e[j] * pinv;
        }

        if (st < 15) {
            *(int4*)&k_lds[cur ^ 1][srow][scg * 8] = kreg0;
            *(int4*)&k_lds[cur ^ 1][32 + srow][scg * 8] = kreg1;
            const unsigned short* pv0 = (const unsigned short*)&vreg0;
            const unsigned short* pv1 = (const unsigned short*)&vreg1;
            #pragma unroll
            for (int j = 0; j < 8; ++j) {
                int row = scg * 8 + j;
                int g0 = ((srow >> 3) ^ j ^ scg) & 7;
                int g1 = ((srow >> 3) ^ 4 ^ j ^ scg) & 7;
                v_lds[cur ^ 1][row][g0 * 8 + (srow & 7)] = pv0[j];
                v_lds[cur ^ 1][row][g1 * 8 + (srow & 7)] = pv1[j];
            }
            bar_lgkm();
        }
    }

    const int b = bh >> 3, h = bh & 7;
    #pragma unroll
    for (int nb = 0; nb < 4; ++nb)
        #pragma unroll
        for (int r = 0; r < 4; ++r) {
            int t = qr + lg * 4 + r;
            obf[((size_t)(b * TT + t)) * 512 + h * 64 + nb * 16 + lr] =
                f2bf(oacc[nb][r] * inv[r]);
        }
}

// ---------------------------------------------------------------------------
// K3: out = obf[4096,512] @ woT^T + bo (MFMA), f32 out. Same dbuf schedule.
// ---------------------------------------------------------------------------
__global__ __launch_bounds__(256) void outproj_mfma_kernel(
    const unsigned short* __restrict__ obf,   // [4096][512]
    const unsigned short* __restrict__ woT,   // [512][512]
    const float* __restrict__ bo, float* __restrict__ out)
{
    __shared__ unsigned short a_s[2][64][64];
    __shared__ unsigned short b_s[2][64][64];
    const int tid = threadIdx.x;
    const int w = tid >> 6, l = tid & 63, lr = l & 15, lg = l >> 4;
    const int n0 = blockIdx.x * 64;
    const int m0 = blockIdx.y * 64;

    f32x4 acc[4];
    #pragma unroll
    for (int nb = 0; nb < 4; ++nb) acc[nb] = (f32x4){0.f, 0.f, 0.f, 0.f};

    int4 areg[2], breg[2];
    #pragma unroll
    for (int rep = 0; rep < 2; ++rep) {
        int idx = rep * 256 + tid;
        int row = idx >> 3, cg = idx & 7;
        areg[rep] = *(const int4*)&obf[(size_t)(m0 + row) * 512 + cg * 8];
        breg[rep] = *(const int4*)&woT[(size_t)(n0 + row) * 512 + cg * 8];
    }
    #pragma unroll
    for (int rep = 0; rep < 2; ++rep) {
        int idx = rep * 256 + tid;
        int row = idx >> 3, cg = idx & 7;
        *(int4*)&a_s[0][row][(cg ^ (row & 7)) * 8] = areg[rep];
        *(int4*)&b_s[0][row][(cg ^ (row & 7)) * 8] = breg[rep];
    }
    bar_lgkm();

    for (int kc = 0; kc < 8; ++kc) {
        const int cur = kc & 1;
        if (kc < 7) {
            int k0 = (kc + 1) * 64;
            #pragma unroll
            for (int rep = 0; rep < 2; ++rep) {
                int idx = rep * 256 + tid;
                int row = idx >> 3, cg = idx & 7;
                areg[rep] = *(const int4*)&obf[(size_t)(m0 + row) * 512 + k0 + cg * 8];
                breg[rep] = *(const int4*)&woT[(size_t)(n0 + row) * 512 + k0 + cg * 8];
            }
        }
        #pragma unroll
        for (int ks = 0; ks < 2; ++ks) {
            int arow = w * 16 + lr;
            bf8_t af = *(const bf8_t*)&a_s[cur][arow][((ks*4 + lg) ^ (arow & 7)) * 8];
            #pragma unroll
            for (int nb = 0; nb < 4; ++nb) {
                int brow = nb * 16 + lr;
                bf8_t bf = *(const bf8_t*)&b_s[cur][brow][((ks*4 + lg) ^ (brow & 7)) * 8];
                acc[nb] = __builtin_amdgcn_mfma_f32_16x16x32_bf16(af, bf, acc[nb], 0, 0, 0);
            }
        }
        if (kc < 7) {
            #pragma unroll
            for (int rep = 0; rep < 2; ++rep) {
                int idx = rep * 256 + tid;
                int row = idx >> 3, cg = idx & 7;
                *(int4*)&a_s[cur ^ 1][row][(cg ^ (row & 7)) * 8] = areg[rep];
                *(int4*)&b_s[cur ^ 1][row][(cg ^ (row & 7)) * 8] = breg[rep];
            }
            bar_lgkm();
        }
    }

    #pragma unroll
    for (int nb = 0; nb < 4; ++nb) {
        float bb = bo[n0 + nb * 16 + lr];
        #pragma unroll
        for (int r = 0; r < 4; ++r) {
            int m = m0 + w * 16 + lg * 4 + r;
            out[(size_t)m * 512 + n0 + nb * 16 + lr] = acc[nb][r] + bb;
        }
    }
}

// ---------------------------------------------------------------------------
extern "C" void kernel_launch(void* const* d_in, const int* in_sizes, int n_in,
                              void* d_out, int out_size, void* d_ws, size_t ws_size,
                              hipStream_t stream)
{
    const float* x    = (const float*)d_in[0];
    const float* Wq_w = (const float*)d_in[1];
    const float* Wq_b = (const float*)d_in[2];
    const float* Wk_w = (const float*)d_in[3];
    const float* Wk_b = (const float*)d_in[4];
    const float* Wv_w = (const float*)d_in[5];
    const float* Wv_b = (const float*)d_in[6];
    const float* Ws_w = (const float*)d_in[7];
    const float* Ws_b = (const float*)d_in[8];
    const float* Wo_w = (const float*)d_in[9];
    const float* Wo_b = (const float*)d_in[10];

    float* out    = (float*)d_out;                      // [B,T,D]
    float* series = out + (size_t)BB*TT*DD;             // [B,H,T,T]
    float* prior  = series + (size_t)BB*HH*TT*TT;       // [B,H,T,T]
    float* sigma  = prior + (size_t)BB*HH*TT*TT;        // [B,H,T]

    const size_t nx = (size_t)BB*TT*DD;                 // 2,097,152
    unsigned short* xbf = (unsigned short*)d_ws;        // [4096][512]
    unsigned short* wt  = xbf + nx;                     // [1600][512]
    unsigned short* woT = wt + (size_t)1600*512;        // [512][512]
    unsigned short* qbf = woT + (size_t)512*512;        // [B,H,T,64]
    unsigned short* kbf = qbf + nx;
    unsigned short* vbf = kbf + nx;
    unsigned short* obf = vbf + nx;                     // [4096][512]

    prep_kernel<<<2049, 256, 0, stream>>>(
        x, Wq_w, Wk_w, Wv_w, Wo_w, Ws_w, xbf, wt, woT);

    proj_mfma_kernel<<<dim3(25, 64), 256, 0, stream>>>(
        xbf, wt, Wq_b, Wk_b, Wv_b, Ws_b, qbf, kbf, vbf, sigma);

    attn_kernel<<<dim3(16, 32), 256, 0, stream>>>(
        qbf, kbf, vbf, sigma, series, prior, obf);

    outproj_mfma_kernel<<<dim3(8, 64), 256, 0, stream>>>(obf, woT, Wo_b, out);
}